// Round 2
// baseline (102.795 us; speedup 1.0000x reference)
//
#include <hip/hip_runtime.h>
#include <math.h>

// Problem constants (from reference): B=8192, V=8, J=32
#define B_TOT 8192
#define V_N 8
#define J_N 32

// loss hyperparams
#define SCALE_KPS 0.1f
#define THRESH 100.0f
#define THRESH_BETA 63.09573444801932f  // 100^0.9

// One block per batch b. 256 threads: thread t -> (v = t>>5, j = t&31).
// Stages cam_preds (96f), kps_world (96f), K (72f) in LDS; initial_keypoints
// loaded as coalesced float2 per thread. Per-view reduction via shfl_xor
// within 32-lane groups; per-block partial written to d_ws.
__global__ __launch_bounds__(256) void qpl_main(
    const float* __restrict__ Kmat,   // [B,V,3,3]
    const float* __restrict__ cam,    // [B,V,3,4]
    const float* __restrict__ kps,    // [B,J,3]
    const float* __restrict__ init,   // [B,V,J,2]
    float* __restrict__ partial)      // [B] in d_ws
{
    __shared__ float s_cam[96];
    __shared__ float s_kps[96];
    __shared__ float s_K[72];
    __shared__ float s_contrib[V_N];

    const int b   = blockIdx.x;
    const int tid = threadIdx.x;
    const int v   = tid >> 5;
    const int j   = tid & 31;

    // cooperative staging: 264 elements on 256 threads -> threads 0..7 load 2
    if (tid < 96)       s_cam[tid]       = cam[b * 96 + tid];
    else if (tid < 192) s_kps[tid - 96]  = kps[b * 96 + (tid - 96)];
    else                s_K[tid - 192]   = Kmat[b * 72 + (tid - 192)];  // 0..63
    if (tid < 8)        s_K[64 + tid]    = Kmat[b * 72 + 64 + tid];     // 64..71

    // coalesced: 256 float2 = 2048B contiguous per block
    const float2 ik = ((const float2*)(init + (size_t)b * (V_N * J_N * 2)))[tid];

    __syncthreads();

    const float x = s_kps[j * 3 + 0];
    const float y = s_kps[j * 3 + 1];
    const float z = s_kps[j * 3 + 2];

    const float* c = s_cam + v * 12;           // [3,4] row-major
    const float cp0 = c[0] * x + c[1] * y + c[2]  * z + c[3];
    const float cp1 = c[4] * x + c[5] * y + c[6]  * z + c[7];
    const float cp2 = c[8] * x + c[9] * y + c[10] * z + c[11];

    const float* k = s_K + v * 9;              // [3,3] row-major
    const float i0 = k[0] * cp0 + k[1] * cp1 + k[2] * cp2;
    const float i1 = k[3] * cp0 + k[4] * cp1 + k[5] * cp2;
    const float i2 = k[6] * cp0 + k[7] * cp1 + k[8] * cp2;

    const float p0 = i0 / i2;
    const float p1 = i1 / i2;

    float d0 = (p0 - ik.x) * SCALE_KPS; d0 *= d0;
    float d1 = (p1 - ik.y) * SCALE_KPS; d1 *= d1;
    const float s0 = (d0 > THRESH) ? powf(d0, 0.1f) * THRESH_BETA : d0;
    const float s1 = (d1 > THRESH) ? powf(d1, 0.1f) * THRESH_BETA : d1;

    float sum_diff = s0 + s1;
    float sum_p2   = p0 * p0 + p1 * p1;
    float sum_i2   = ik.x * ik.x + ik.y * ik.y;

    // reduce across the 32 joints of this view (masks <=16 stay in-group)
    #pragma unroll
    for (int m = 16; m >= 1; m >>= 1) {
        sum_diff += __shfl_xor(sum_diff, m);
        sum_p2   += __shfl_xor(sum_p2, m);
        sum_i2   += __shfl_xor(sum_i2, m);
    }

    if (j == 0) {
        const float penal = fabsf(sqrtf(sum_p2) / sqrtf(sum_i2) - 1.0f);
        s_contrib[v] = (sum_diff * 0.5f) * penal;
    }
    __syncthreads();

    if (tid == 0) {
        float t = 0.0f;
        #pragma unroll
        for (int vv = 0; vv < V_N; ++vv) t += s_contrib[vv];
        partial[b] = t;
    }
}

// Single-block final reduction of the 8192 per-batch partials.
__global__ __launch_bounds__(256) void qpl_reduce(
    const float* __restrict__ partial, float* __restrict__ out)
{
    __shared__ float s_w[4];
    float t = 0.0f;
    for (int i = threadIdx.x; i < B_TOT; i += 256) t += partial[i];

    #pragma unroll
    for (int m = 32; m >= 1; m >>= 1) t += __shfl_xor(t, m);

    if ((threadIdx.x & 63) == 0) s_w[threadIdx.x >> 6] = t;
    __syncthreads();

    if (threadIdx.x == 0) {
        const float tot = s_w[0] + s_w[1] + s_w[2] + s_w[3];
        out[0] = tot * (1.0f / (float)(B_TOT * V_N));
    }
}

extern "C" void kernel_launch(void* const* d_in, const int* in_sizes, int n_in,
                              void* d_out, int out_size, void* d_ws, size_t ws_size,
                              hipStream_t stream) {
    const float* Kmat = (const float*)d_in[0];  // [B,V,3,3]
    const float* cam  = (const float*)d_in[1];  // [B,V,3,4]
    const float* kps  = (const float*)d_in[2];  // [B,J,3]
    const float* init = (const float*)d_in[3];  // [B,V,J,2]
    float* partial = (float*)d_ws;              // B_TOT floats = 32 KB
    float* out     = (float*)d_out;

    qpl_main<<<B_TOT, 256, 0, stream>>>(Kmat, cam, kps, init, partial);
    qpl_reduce<<<1, 256, 0, stream>>>(partial, out);
}

// Round 4
// 79.846 us; speedup vs baseline: 1.2874x; 1.2874x over previous
//
#include <hip/hip_runtime.h>
#include <math.h>

// Problem constants: B=8192, V=8, J=32
#define B_TOT 8192
#define V_N 8
#define J_N 32

#define SCALE_KPS 0.1f
#define THRESH 100.0f
#define THRESH_BETA 63.09573444801932f  // 100^0.9

// smooth-MSE branch: d>100 ? d^0.1 * 100^0.9 : d
// __builtin_amdgcn_logf = v_log_f32 (log2), __builtin_amdgcn_exp2f = v_exp_f32 (2^x)
__device__ __forceinline__ float smooth_term(float d) {
    return (d > THRESH)
        ? __builtin_amdgcn_exp2f(0.1f * __builtin_amdgcn_logf(d)) * THRESH_BETA
        : d;
}

// One WAVE per batch. Lane l: j = l&31, half h = l>>5.
// Half h handles views {h, h+2, h+4, h+6} (unrolled). No LDS / barriers in
// the per-batch path; matrix loads are half-wave-uniform (HW-merged
// broadcast). All reductions are shfl_xor butterflies.
// Block = 4 waves = 4 batches; one partial per block -> partial[2048].
__global__ __launch_bounds__(256) void qpl_fused(
    const float* __restrict__ Kmat,   // [B,V,3,3]
    const float* __restrict__ cam,    // [B,V,3,4]
    const float* __restrict__ kps,    // [B,J,3]
    const float* __restrict__ init,   // [B,V,J,2]
    float* __restrict__ partial)      // [gridDim.x] in d_ws
{
    __shared__ float s_acc[4];

    const int tid  = threadIdx.x;
    const int wave = tid >> 6;
    const int lane = tid & 63;
    const int jj   = lane & 31;
    const int h    = lane >> 5;
    const int b    = blockIdx.x * 4 + wave;   // 2048*4 = 8192

    // joint coords: both halves load identical addresses -> merged
    const float* kp = kps + b * (J_N * 3) + jj * 3;
    const float x = kp[0];
    const float y = kp[1];
    const float z = kp[2];

    const float*  camb  = cam  + (size_t)b * (V_N * 12);
    const float*  Kb    = Kmat + (size_t)b * (V_N * 9);
    const float2* initb = (const float2*)(init + (size_t)b * (V_N * J_N * 2));

    float acc = 0.0f;

    #pragma unroll
    for (int vi = 0; vi < 4; ++vi) {
        const int v = h + vi * 2;

        // cam[b,v]: 12 floats, 16B-aligned (v*48B) -> 3x float4 broadcast
        const float4 c0 = ((const float4*)(camb + v * 12))[0];
        const float4 c1 = ((const float4*)(camb + v * 12))[1];
        const float4 c2 = ((const float4*)(camb + v * 12))[2];
        // K[b,v]: 9 floats, v*36B NOT 16B-aligned for odd v -> scalar loads
        const float* kv = Kb + v * 9;
        const float k0 = kv[0], k1 = kv[1], k2 = kv[2];
        const float k3 = kv[3], k4 = kv[4], k5 = kv[5];
        const float k6 = kv[6], k7 = kv[7], k8 = kv[8];

        // init[b,v,jj]: half-wave reads 256B contiguous, 8B-aligned
        const float2 ik = initb[v * J_N + jj];

        const float cp0 = c0.x * x + c0.y * y + c0.z * z + c0.w;
        const float cp1 = c1.x * x + c1.y * y + c1.z * z + c1.w;
        const float cp2 = c2.x * x + c2.y * y + c2.z * z + c2.w;

        const float i0 = k0 * cp0 + k1 * cp1 + k2 * cp2;
        const float i1 = k3 * cp0 + k4 * cp1 + k5 * cp2;
        const float i2 = k6 * cp0 + k7 * cp1 + k8 * cp2;

        float r = __builtin_amdgcn_rcpf(i2);
        r = r * (2.0f - i2 * r);          // one Newton step
        const float p0 = i0 * r;
        const float p1 = i1 * r;

        float d0 = (p0 - ik.x) * SCALE_KPS; d0 *= d0;
        float d1 = (p1 - ik.y) * SCALE_KPS; d1 *= d1;

        float sum_diff = smooth_term(d0) + smooth_term(d1);
        float sum_p2   = p0 * p0 + p1 * p1;
        float sum_i2   = ik.x * ik.x + ik.y * ik.y;

        // butterfly over the 32 joints of this half (bit5 preserved)
        #pragma unroll
        for (int m = 16; m >= 1; m >>= 1) {
            sum_diff += __shfl_xor(sum_diff, m);
            sum_p2   += __shfl_xor(sum_p2, m);
            sum_i2   += __shfl_xor(sum_i2, m);
        }
        // all lanes of the half now hold the view sums (uniform)
        const float penal = fabsf(sqrtf(sum_p2 / sum_i2) - 1.0f);
        acc += (sum_diff * 0.5f) * penal;
    }

    // combine the two halves (views 0,2,4,6 + 1,3,5,7)
    acc += __shfl_xor(acc, 32);

    if (lane == 0) s_acc[wave] = acc;
    __syncthreads();
    if (tid == 0)
        partial[blockIdx.x] = s_acc[0] + s_acc[1] + s_acc[2] + s_acc[3];
}

// Fold 2048 per-block partials into the scalar output.
__global__ __launch_bounds__(256) void qpl_reduce(
    const float* __restrict__ partial, float* __restrict__ out)
{
    __shared__ float s_w[4];
    float t = 0.0f;
    #pragma unroll
    for (int k = 0; k < 8; ++k) t += partial[threadIdx.x + k * 256];

    #pragma unroll
    for (int m = 32; m >= 1; m >>= 1) t += __shfl_xor(t, m);

    if ((threadIdx.x & 63) == 0) s_w[threadIdx.x >> 6] = t;
    __syncthreads();

    if (threadIdx.x == 0) {
        const float tot = s_w[0] + s_w[1] + s_w[2] + s_w[3];
        out[0] = tot * (1.0f / (float)(B_TOT * V_N));
    }
}

extern "C" void kernel_launch(void* const* d_in, const int* in_sizes, int n_in,
                              void* d_out, int out_size, void* d_ws, size_t ws_size,
                              hipStream_t stream) {
    const float* Kmat = (const float*)d_in[0];  // [B,V,3,3]
    const float* cam  = (const float*)d_in[1];  // [B,V,3,4]
    const float* kps  = (const float*)d_in[2];  // [B,J,3]
    const float* init = (const float*)d_in[3];  // [B,V,J,2]
    float* partial = (float*)d_ws;              // 2048 floats
    float* out     = (float*)d_out;

    qpl_fused<<<B_TOT / 4, 256, 0, stream>>>(Kmat, cam, kps, init, partial);
    qpl_reduce<<<1, 256, 0, stream>>>(partial, out);
}

// Round 6
// 76.593 us; speedup vs baseline: 1.3421x; 1.0425x over previous
//
#include <hip/hip_runtime.h>
#include <math.h>

// Problem constants: B=8192, V=8, J=32
#define B_TOT 8192
#define V_N 8
#define J_N 32

#define SCALE_KPS 0.1f
#define THRESH 100.0f
#define THRESH_BETA 63.09573444801932f  // 100^0.9

// smooth-MSE branch: d>100 ? d^0.1 * 100^0.9 : d
// __builtin_amdgcn_logf = v_log_f32 (log2), __builtin_amdgcn_exp2f = v_exp_f32
__device__ __forceinline__ float smooth_term(float d) {
    return (d > THRESH)
        ? __builtin_amdgcn_exp2f(0.1f * __builtin_amdgcn_logf(d)) * THRESH_BETA
        : d;
}

// One WAVE per batch. Lane l: view v = l>>3, joint-group t = l&7 (joints
// 4t..4t+3 processed serially). All big loads are float4 / fully coalesced:
//   init: 32B/lane -> contiguous 2KB per wave (global_load_dwordx4 x2)
//   kps : 48B per group as 3x float4, 8-way broadcast across view-groups
//   cam : 3x float4, uniform within each 8-lane group
// Reduction per view: 3-level shfl_xor over 8 lanes. View-group fold via
// xor 8/16/32 adds each DISTINCT view exactly once (no overcount — R5 bug
// was an erroneous /8 here). No LDS/barriers in hot path.
// Block = 4 waves = 4 batches; partial[2048].
__global__ __launch_bounds__(256) void qpl_fused(
    const float* __restrict__ Kmat,   // [B,V,3,3]
    const float* __restrict__ cam,    // [B,V,3,4]
    const float* __restrict__ kps,    // [B,J,3]
    const float* __restrict__ init,   // [B,V,J,2]
    float* __restrict__ partial)      // [gridDim.x] in d_ws
{
    __shared__ float s_acc[4];

    const int tid  = threadIdx.x;
    const int wave = tid >> 6;
    const int lane = tid & 63;
    const int v    = lane >> 3;   // view 0..7
    const int t    = lane & 7;    // joint group: joints 4t..4t+3
    const int b    = blockIdx.x * 4 + wave;

    // kps[b, 4t..4t+3, :]: floats [12t, 12t+12), 16B-aligned (48B stride)
    const float4* kp4 = (const float4*)(kps + (size_t)b * (J_N * 3) + t * 12);
    const float4 f0 = kp4[0], f1 = kp4[1], f2 = kp4[2];

    // cam[b,v]: 48B, 16B-aligned, uniform within 8-lane group
    const float* cv = cam + (size_t)b * (V_N * 12) + v * 12;
    const float4 c0 = ((const float4*)cv)[0];
    const float4 c1 = ((const float4*)cv)[1];
    const float4 c2 = ((const float4*)cv)[2];

    // K[b,v]: 36B stride -> odd v misaligned for float4; scalar broadcast loads
    const float* kv = Kmat + (size_t)b * (V_N * 9) + v * 9;
    const float k0 = kv[0], k1 = kv[1], k2 = kv[2];
    const float k3 = kv[3], k4 = kv[4], k5 = kv[5];
    const float k6 = kv[6], k7 = kv[7], k8 = kv[8];

    // init[b, v, 4t..4t+3, :]: lane reads bytes [32*lane, 32*lane+32)
    const float4* ib = (const float4*)(init + (size_t)b * (V_N * J_N * 2) + lane * 8);
    const float4 q0 = ib[0], q1 = ib[1];

    const float xs[4]  = {f0.x, f0.w, f1.z, f2.y};
    const float ys[4]  = {f0.y, f1.x, f1.w, f2.z};
    const float zs[4]  = {f0.z, f1.y, f2.x, f2.w};
    const float ikx[4] = {q0.x, q0.z, q1.x, q1.z};
    const float iky[4] = {q0.y, q0.w, q1.y, q1.w};

    float sum_diff = 0.0f, sum_p2 = 0.0f, sum_i2 = 0.0f;

    #pragma unroll
    for (int m = 0; m < 4; ++m) {
        const float cp0 = c0.x * xs[m] + c0.y * ys[m] + c0.z * zs[m] + c0.w;
        const float cp1 = c1.x * xs[m] + c1.y * ys[m] + c1.z * zs[m] + c1.w;
        const float cp2 = c2.x * xs[m] + c2.y * ys[m] + c2.z * zs[m] + c2.w;

        const float i0 = k0 * cp0 + k1 * cp1 + k2 * cp2;
        const float i1 = k3 * cp0 + k4 * cp1 + k5 * cp2;
        const float i2 = k6 * cp0 + k7 * cp1 + k8 * cp2;

        const float r  = __builtin_amdgcn_rcpf(i2);   // 1-ulp, tolerance is 358 abs
        const float p0 = i0 * r;
        const float p1 = i1 * r;

        float d0 = (p0 - ikx[m]) * SCALE_KPS; d0 *= d0;
        float d1 = (p1 - iky[m]) * SCALE_KPS; d1 *= d1;

        sum_diff += smooth_term(d0) + smooth_term(d1);
        sum_p2   += p0 * p0 + p1 * p1;
        sum_i2   += ikx[m] * ikx[m] + iky[m] * iky[m];
    }

    // reduce over the 8 lanes of this view-group (masks 1,2,4 stay in-group)
    #pragma unroll
    for (int m = 1; m <= 4; m <<= 1) {
        sum_diff += __shfl_xor(sum_diff, m);
        sum_p2   += __shfl_xor(sum_p2, m);
        sum_i2   += __shfl_xor(sum_i2, m);
    }

    const float penal = fabsf(sqrtf(sum_p2 * __builtin_amdgcn_rcpf(sum_i2)) - 1.0f);
    float acc = (sum_diff * 0.5f) * penal;   // uniform within 8-lane group

    // fold the 8 DISTINCT view-groups: each view added exactly once
    acc += __shfl_xor(acc, 8);
    acc += __shfl_xor(acc, 16);
    acc += __shfl_xor(acc, 32);

    if (lane == 0) s_acc[wave] = acc;
    __syncthreads();
    if (tid == 0)
        partial[blockIdx.x] = s_acc[0] + s_acc[1] + s_acc[2] + s_acc[3];
}

// Fold 2048 per-block partials into the scalar output.
__global__ __launch_bounds__(256) void qpl_reduce(
    const float* __restrict__ partial, float* __restrict__ out)
{
    __shared__ float s_w[4];
    float t = 0.0f;
    #pragma unroll
    for (int k = 0; k < 8; ++k) t += partial[threadIdx.x + k * 256];

    #pragma unroll
    for (int m = 32; m >= 1; m >>= 1) t += __shfl_xor(t, m);

    if ((threadIdx.x & 63) == 0) s_w[threadIdx.x >> 6] = t;
    __syncthreads();

    if (threadIdx.x == 0) {
        const float tot = s_w[0] + s_w[1] + s_w[2] + s_w[3];
        out[0] = tot * (1.0f / (float)(B_TOT * V_N));
    }
}

extern "C" void kernel_launch(void* const* d_in, const int* in_sizes, int n_in,
                              void* d_out, int out_size, void* d_ws, size_t ws_size,
                              hipStream_t stream) {
    const float* Kmat = (const float*)d_in[0];  // [B,V,3,3]
    const float* cam  = (const float*)d_in[1];  // [B,V,3,4]
    const float* kps  = (const float*)d_in[2];  // [B,J,3]
    const float* init = (const float*)d_in[3];  // [B,V,J,2]
    float* partial = (float*)d_ws;              // 2048 floats
    float* out     = (float*)d_out;

    qpl_fused<<<B_TOT / 4, 256, 0, stream>>>(Kmat, cam, kps, init, partial);
    qpl_reduce<<<1, 256, 0, stream>>>(partial, out);
}